// Round 14
// baseline (192.264 us; speedup 1.0000x reference)
//
#include <hip/hip_runtime.h>
#include <math.h>

// Problem constants: B=64, D=512, H=W=32 -> N=1024, NH=8, DH=64
#define BATCH  64
#define DCH    512
#define NPOS   1024
#define NH     8
#define NSPLIT 32
#define NRANGE 32      // n per wave-tile

// ---------------------------------------------------------------------------
// K1 (prep): blocks 0-1: wqT[c*8+h] = 0.125 * sum_d q[h,d]*Wkv[c,h*64+d]
//            blocks 2-5: bias[h*1024+n] = 0.125*(q.pe[n] + q.bkv)
// ---------------------------------------------------------------------------
__global__ __launch_bounds__(256) void k_prep(const float* __restrict__ q,
                                              const float* __restrict__ Wkv,
                                              const float* __restrict__ bkv,
                                              float* __restrict__ wqT,
                                              float* __restrict__ bias) {
    int blk = blockIdx.x;
    if (blk < 2) {
        int c = blk * 256 + threadIdx.x;
        const float4* wrow = (const float4*)(Wkv + (size_t)c * (2 * DCH));
        const float4* q4   = (const float4*)q;
        #pragma unroll
        for (int h = 0; h < NH; ++h) {
            float s = 0.f;
            #pragma unroll
            for (int d4 = 0; d4 < 16; ++d4) {
                float4 a = q4[h * 16 + d4];
                float4 w = wrow[h * 16 + d4];
                s = fmaf(a.x, w.x, fmaf(a.y, w.y, fmaf(a.z, w.z, fmaf(a.w, w.w, s))));
            }
            wqT[c * NH + h] = 0.125f * s;
        }
    } else {
        int n = (blk - 2) * 256 + threadIdx.x;
        float pq[NH];
        #pragma unroll
        for (int h = 0; h < NH; ++h) pq[h] = 0.f;
        const float kfac2 = -13.2877123795494f / 64.f;   // -log2(10000)/64
        for (int i = 0; i < 32; ++i) {
            float dt = exp2f((float)(2 * i) * kfac2);
            float ang = (float)n * dt;
            float sn, cs;
            sincosf(ang, &sn, &cs);
            #pragma unroll
            for (int h = 0; h < NH; ++h)
                pq[h] = fmaf(q[h * 64 + 2 * i], sn,
                        fmaf(q[h * 64 + 2 * i + 1], cs, pq[h]));
        }
        #pragma unroll
        for (int h = 0; h < NH; ++h) {
            float bq = 0.f;
            #pragma unroll 8
            for (int d = 0; d < 64; ++d)
                bq = fmaf(q[h * 64 + d], bkv[h * 64 + d], bq);
            bias[h * NPOS + n] = 0.125f * (pq[h] + bq);
        }
    }
}

// ---------------------------------------------------------------------------
// K2 (flash, barrier-free waves): grid (8, B) = 512 blocks x 256 thr
// (4 waves), 2 blocks/CU = 8 independent waves/CU. Wave w owns tile
// ns = tg*4+w (32 n) for batch b, END TO END:
//   pass 1 (dots): lane=(rg=l>>3, n8=l&7); rows 8k+rg, quad n8; LDS wq
//     broadcast; xor8/16/32 reduce -> every lane holds s[h][own quad].
//   softmax: fixed ref m=0 (|s| < ~4), p in registers; Z via xor1/2/4;
//     p -> wave-local LDS slice (same-wave write/read, no barrier).
//   pass 2 (PV): lane = c (c-per-lane, full n in-thread -> NO cross-lane
//     reduce); x re-read is L2/L3-resident; coalesced stores.
// Only ONE __syncthreads (initial wqs staging). No phase lockstep.
// ---------------------------------------------------------------------------
__global__ __launch_bounds__(256) void k_flash(const float* __restrict__ x,
                                               const float* __restrict__ wqT,
                                               const float* __restrict__ bias,
                                               float* __restrict__ apart,  // [NSPLIT][B][NH][DCH]
                                               float* __restrict__ zz) {   // [NSPLIT][B][NH]
    __shared__ float wqs[DCH * NH];         // 16 KB  [c*8+h]
    __shared__ float pls[4][NH][NRANGE];    // 4 KB   per-wave p slices

    int b = blockIdx.y, tg = blockIdx.x;
    int t = threadIdx.x, w = t >> 6, lane = t & 63;
    int ns = tg * 4 + w;
    int n0 = ns * NRANGE;
    int rg = lane >> 3, n8 = lane & 7;

    {   // stage wq -> LDS (coalesced float4)
        const float4* s4 = (const float4*)wqT;
        float4* d4 = (float4*)wqs;
        #pragma unroll
        for (int i = 0; i < 4; ++i) d4[t + 256 * i] = s4[t + 256 * i];
    }
    __syncthreads();   // the only block barrier

    // ---------------- pass 1: dots ----------------
    const float* gx = x + ((size_t)b * DCH + rg) * NPOS + n0 + n8 * 4;
    float acc[NH][4];
    #pragma unroll
    for (int h = 0; h < NH; ++h)
        #pragma unroll
        for (int e = 0; e < 4; ++e) acc[h][e] = 0.f;

    #pragma unroll 8
    for (int k = 0; k < 64; ++k) {
        float4 xv = *(const float4*)(gx + (size_t)(8 * k) * NPOS);
        int c = 8 * k + rg;
        float wv[8];
        *(float4*)&wv[0] = *(const float4*)&wqs[c * 8];
        *(float4*)&wv[4] = *(const float4*)&wqs[c * 8 + 4];
        #pragma unroll
        for (int h = 0; h < NH; ++h) {
            acc[h][0] = fmaf(xv.x, wv[h], acc[h][0]);
            acc[h][1] = fmaf(xv.y, wv[h], acc[h][1]);
            acc[h][2] = fmaf(xv.z, wv[h], acc[h][2]);
            acc[h][3] = fmaf(xv.w, wv[h], acc[h][3]);
        }
    }
    // reduce over rg (lane bits 3,4,5) — all lanes end with the full sum
    #pragma unroll
    for (int h = 0; h < NH; ++h)
        #pragma unroll
        for (int e = 0; e < 4; ++e) {
            float v = acc[h][e];
            v += __shfl_xor(v, 8);
            v += __shfl_xor(v, 16);
            v += __shfl_xor(v, 32);
            acc[h][e] = v;
        }

    // ---------------- softmax numerators (fixed ref m=0) ----------------
    {
        float zh[NH];
        #pragma unroll
        for (int h = 0; h < NH; ++h) {
            float4 bb = *(const float4*)(bias + h * NPOS + n0 + n8 * 4);
            float p0 = expf(acc[h][0] + bb.x);
            float p1 = expf(acc[h][1] + bb.y);
            float p2 = expf(acc[h][2] + bb.z);
            float p3 = expf(acc[h][3] + bb.w);
            acc[h][0] = p0; acc[h][1] = p1; acc[h][2] = p2; acc[h][3] = p3;
            float z = (p0 + p1) + (p2 + p3);
            z += __shfl_xor(z, 1);
            z += __shfl_xor(z, 2);
            z += __shfl_xor(z, 4);
            zh[h] = z;
        }
        if (rg == 0) {
            #pragma unroll
            for (int h = 0; h < NH; ++h)
                *(float4*)&pls[w][h][n8 * 4] =
                    make_float4(acc[h][0], acc[h][1], acc[h][2], acc[h][3]);
        }
        if (lane == 0) {
            #pragma unroll
            for (int h = 0; h < NH; ++h)
                zz[((size_t)ns * BATCH + b) * NH + h] = zh[h];
        }
    }
    // same-wave LDS write->read: compiler-inserted lgkmcnt orders it; no barrier

    // ---------------- pass 2: PV, c-per-lane ----------------
    float con[8][NH];
    #pragma unroll
    for (int cg = 0; cg < 8; ++cg)
        #pragma unroll
        for (int h = 0; h < NH; ++h) con[cg][h] = 0.f;

    const float* xr = x + ((size_t)b * DCH + lane) * NPOS + n0;
    #pragma unroll
    for (int j = 0; j < 8; ++j) {
        float4 pj[NH];
        #pragma unroll
        for (int h = 0; h < NH; ++h)
            pj[h] = *(const float4*)&pls[w][h][j * 4];
        #pragma unroll
        for (int cg = 0; cg < 8; ++cg) {
            float4 xv = *(const float4*)(xr + (size_t)(cg * 64) * NPOS + j * 4);
            #pragma unroll
            for (int h = 0; h < NH; ++h)
                con[cg][h] = fmaf(xv.x, pj[h].x, fmaf(xv.y, pj[h].y,
                             fmaf(xv.z, pj[h].z, fmaf(xv.w, pj[h].w, con[cg][h]))));
        }
    }

    size_t abase = ((size_t)ns * BATCH + b) * (NH * DCH);
    #pragma unroll
    for (int cg = 0; cg < 8; ++cg)
        #pragma unroll
        for (int h = 0; h < NH; ++h)
            apart[abase + (size_t)h * DCH + cg * 64 + lane] = con[cg][h];
}

// ---------------------------------------------------------------------------
// K3 (comb): Z-normalize + sum 32 partials + output GEMV. grid (B, 2),
// 512 thr. Fixed-ref softmax -> no exp/max here, just Z = sum of zz.
// ---------------------------------------------------------------------------
__global__ __launch_bounds__(512) void k_comb(const float* __restrict__ apart,
                                              const float* __restrict__ zz,
                                              const float* __restrict__ Wkv,
                                              const float* __restrict__ bkv,
                                              float* __restrict__ out) {
    __shared__ float as[2048];       // this half's 4 heads x 512 c
    __shared__ float red[2][256];
    int b = blockIdx.x, half = blockIdx.y, t = threadIdx.x;

    int e0 = t * 4;                  // local [0,2048)
    int h  = half * 4 + (t >> 7);    // global head of this thread's 4 elems

    float Z = 0.f;
    #pragma unroll
    for (int j = 0; j < NSPLIT; ++j)
        Z += zz[((size_t)j * BATCH + b) * NH + h];
    float invZ = 1.f / Z;

    float v0 = 0.f, v1 = 0.f, v2 = 0.f, v3 = 0.f;
    #pragma unroll 8
    for (int j = 0; j < NSPLIT; ++j) {
        const float* src = apart + ((size_t)j * BATCH + b) * (NH * DCH)
                         + half * 2048 + e0;
        float4 lo = *(const float4*)src;
        v0 += lo.x; v1 += lo.y; v2 += lo.z; v3 += lo.w;
    }
    as[e0]     = v0 * invZ;
    as[e0 + 1] = v1 * invZ;
    as[e0 + 2] = v2 * invZ;
    as[e0 + 3] = v3 * invZ;
    __syncthreads();

    int o  = t & 255;
    int cp = t >> 8;
    int hd = half * 256 + o;                 // output column
    float a0 = 0.f, a1 = 0.f, a2 = 0.f, a3 = 0.f;
    const float* wp  = Wkv + DCH + hd;
    const float* apr = as + (o >> 6) * DCH;  // local head = o>>6
    int cbeg = cp * 256;
    #pragma unroll 4
    for (int c = cbeg; c < cbeg + 256; c += 4) {
        a0 = fmaf(apr[c],     wp[(size_t)c * (2 * DCH)],       a0);
        a1 = fmaf(apr[c + 1], wp[(size_t)(c + 1) * (2 * DCH)], a1);
        a2 = fmaf(apr[c + 2], wp[(size_t)(c + 2) * (2 * DCH)], a2);
        a3 = fmaf(apr[c + 3], wp[(size_t)(c + 3) * (2 * DCH)], a3);
    }
    red[cp][o] = (a0 + a1) + (a2 + a3);
    __syncthreads();
    if (t < 256) {
        int hd2 = half * 256 + t;
        out[(size_t)b * DCH + hd2] = bkv[DCH + hd2] + red[0][t] + red[1][t];
    }
}

// ---------------------------------------------------------------------------
extern "C" void kernel_launch(void* const* d_in, const int* in_sizes, int n_in,
                              void* d_out, int out_size, void* d_ws, size_t ws_size,
                              hipStream_t stream) {
    const float* x   = (const float*)d_in[0];   // (64, 512, 32, 32)
    const float* q   = (const float*)d_in[1];   // (1, 8, 1, 64)
    const float* Wkv = (const float*)d_in[2];   // (512, 1024)
    const float* bkv = (const float*)d_in[3];   // (1024,)
    float* out = (float*)d_out;                 // (64, 512)

    float* ws    = (float*)d_ws;
    float* wqT   = ws;                                           // 4 K floats
    float* bias  = wqT + DCH * NH;                               // 8 K
    float* apart = bias + NH * NPOS;                             // 32*64*4096 = 33.5 MB
    float* zz    = apart + (size_t)NSPLIT * BATCH * NH * DCH;    // 16 K

    hipLaunchKernelGGL(k_prep,  dim3(6),          dim3(256), 0, stream, q, Wkv, bkv, wqT, bias);
    hipLaunchKernelGGL(k_flash, dim3(8, BATCH),   dim3(256), 0, stream, x, wqT, bias, apart, zz);
    hipLaunchKernelGGL(k_comb,  dim3(BATCH, 2),   dim3(512), 0, stream, apart, zz, Wkv, bkv, out);
}